// Round 2
// baseline (37561.661 us; speedup 1.0000x reference)
//
#include <hip/hip_runtime.h>
#include <hip/hip_bf16.h>

#define BB 16
#define TT 1024
#define FF 128
#define RR 2048
#define HALF 1024
#define NBLK 256
#define NTHR 512

// Zero the barrier counter and init h0[b][r] = start[r].
__global__ void init_kernel(float* __restrict__ h, const float* __restrict__ start,
                            unsigned* __restrict__ cnt) {
    int idx = blockIdx.x * blockDim.x + threadIdx.x;
    if (idx == 0) *cnt = 0u;
    if (idx < BB * RR) h[idx] = start[idx & (RR - 1)];
}

// Persistent ESN kernel: 256 blocks x 512 threads, 1 block/CU (cooperative).
// Block owns 8 rows. Wave = (rg: 4 rows) x (bg: 4 batches). Quarter-wave
// (16 lanes) owns one batch; lane kl sweeps k = kl*4 + j*64. All 4
// quarter-waves issue identical W addresses -> VMEM dedup (W read once/wave).
__global__ __launch_bounds__(NTHR, 2) void esn_persist(
    const float* __restrict__ inputs,   // [B,T,F]
    const float* __restrict__ Win,      // [R,F]
    const float* __restrict__ Wrec,     // [R,R]
    const float* __restrict__ bias,     // [R]
    float* __restrict__ hA,             // [B,R]
    float* __restrict__ hB,             // [B,R]
    float* __restrict__ out,            // [B,T,HALF]
    unsigned* __restrict__ cnt)
{
    const int tid  = threadIdx.x;
    const int wave = tid >> 6;           // 0..7
    const int rg   = wave & 1;           // row group
    const int bg   = wave >> 1;          // batch group
    const int qw   = (tid >> 4) & 3;     // quarter-wave
    const int kl   = tid & 15;           // k lane in quarter-wave
    const int b    = bg * 4 + qw;        // 0..15
    const int r0   = blockIdx.x * 8 + rg * 4;
    const bool proj = (blockIdx.x < (NBLK / 2));   // rows < HALF get input proj

    const float* W0 = Wrec + (size_t)(r0 + 0) * RR;
    const float* W1 = Wrec + (size_t)(r0 + 1) * RR;
    const float* W2 = Wrec + (size_t)(r0 + 2) * RR;
    const float* W3 = Wrec + (size_t)(r0 + 3) * RR;

    float my_bias = 0.0f;
    if (kl < 4) my_bias = bias[r0 + kl];

    for (int t = 0; t < TT; ++t) {
        const float* hc = (t & 1) ? hB : hA;
        float*       hn = (t & 1) ? hA : hB;

        float a0 = 0.0f, a1 = 0.0f, a2 = 0.0f, a3 = 0.0f;

        // Fused input projection (k over F=128 = 16 lanes x 4 x 2)
        if (proj) {
            const float* inb = inputs + ((size_t)b * TT + t) * FF;
#pragma unroll
            for (int j = 0; j < 2; ++j) {
                const int k = kl * 4 + j * 64;
                const float4 x  = *reinterpret_cast<const float4*>(inb + k);
                const float4 w0 = *reinterpret_cast<const float4*>(Win + (size_t)(r0 + 0) * FF + k);
                const float4 w1 = *reinterpret_cast<const float4*>(Win + (size_t)(r0 + 1) * FF + k);
                const float4 w2 = *reinterpret_cast<const float4*>(Win + (size_t)(r0 + 2) * FF + k);
                const float4 w3 = *reinterpret_cast<const float4*>(Win + (size_t)(r0 + 3) * FF + k);
                a0 += x.x * w0.x + x.y * w0.y + x.z * w0.z + x.w * w0.w;
                a1 += x.x * w1.x + x.y * w1.y + x.z * w1.z + x.w * w1.w;
                a2 += x.x * w2.x + x.y * w2.y + x.z * w2.z + x.w * w2.w;
                a3 += x.x * w3.x + x.y * w3.y + x.z * w3.z + x.w * w3.w;
            }
        }

        // Recurrent matmul: k = kl*4 + j*64, j = 0..31
        const float* hb = hc + (size_t)b * RR;
#pragma unroll 4
        for (int j = 0; j < 32; ++j) {
            const int k = kl * 4 + j * 64;
            const float4 hv = *reinterpret_cast<const float4*>(hb + k);
            const float4 w0 = *reinterpret_cast<const float4*>(W0 + k);
            const float4 w1 = *reinterpret_cast<const float4*>(W1 + k);
            const float4 w2 = *reinterpret_cast<const float4*>(W2 + k);
            const float4 w3 = *reinterpret_cast<const float4*>(W3 + k);
            a0 = fmaf(hv.x, w0.x, a0); a0 = fmaf(hv.y, w0.y, a0);
            a0 = fmaf(hv.z, w0.z, a0); a0 = fmaf(hv.w, w0.w, a0);
            a1 = fmaf(hv.x, w1.x, a1); a1 = fmaf(hv.y, w1.y, a1);
            a1 = fmaf(hv.z, w1.z, a1); a1 = fmaf(hv.w, w1.w, a1);
            a2 = fmaf(hv.x, w2.x, a2); a2 = fmaf(hv.y, w2.y, a2);
            a2 = fmaf(hv.z, w2.z, a2); a2 = fmaf(hv.w, w2.w, a2);
            a3 = fmaf(hv.x, w3.x, a3); a3 = fmaf(hv.y, w3.y, a3);
            a3 = fmaf(hv.z, w3.z, a3); a3 = fmaf(hv.w, w3.w, a3);
        }

        // Butterfly reduce over the 16-lane quarter-wave (xor of bits 0..3)
#define RED16(v) v += __shfl_xor(v, 1); v += __shfl_xor(v, 2); \
                 v += __shfl_xor(v, 4); v += __shfl_xor(v, 8);
        RED16(a0) RED16(a1) RED16(a2) RED16(a3)
#undef RED16

        // Epilogue: lane kl<4 of each quarter-wave finalizes row r0+kl, batch b
        if (kl < 4) {
            float pre = (kl == 0) ? a0 : (kl == 1) ? a1 : (kl == 2) ? a2 : a3;
            pre += my_bias;
            const int r = r0 + kl;
            const float h_old = hb[r];
            const float v = 0.05f * h_old + 0.95f * tanhf(pre);
            hn[(size_t)b * RR + r] = v;
            if (!proj) out[((size_t)b * TT + t) * HALF + (r - HALF)] = v;
        }

        // Grid barrier: monotonic counter, one atomic per block per step
        __syncthreads();
        if (tid == 0) {
            __hip_atomic_fetch_add(cnt, 1u, __ATOMIC_ACQ_REL, __HIP_MEMORY_SCOPE_AGENT);
            const unsigned target = (unsigned)(t + 1) * NBLK;
            while (__hip_atomic_load(cnt, __ATOMIC_ACQUIRE, __HIP_MEMORY_SCOPE_AGENT) < target) {
                __builtin_amdgcn_s_sleep(2);
            }
        }
        __syncthreads();
    }
}

extern "C" void kernel_launch(void* const* d_in, const int* in_sizes, int n_in,
                              void* d_out, int out_size, void* d_ws, size_t ws_size,
                              hipStream_t stream) {
    const float* inputs = (const float*)d_in[0];   // [B,T,F]
    const float* Win    = (const float*)d_in[1];   // [R,F]
    const float* Wrec   = (const float*)d_in[2];   // [R,R]
    const float* bias   = (const float*)d_in[3];   // [R]
    const float* start  = (const float*)d_in[4];   // [R]
    float* out = (float*)d_out;                    // [B,T,HALF]

    float* hA = (float*)d_ws;                      // [B,R]
    float* hB = hA + (size_t)BB * RR;              // [B,R]
    unsigned* cnt = (unsigned*)(hB + (size_t)BB * RR);

    hipLaunchKernelGGL(init_kernel, dim3(64), dim3(512), 0, stream, hA, start, cnt);

    void* args[] = { (void*)&inputs, (void*)&Win, (void*)&Wrec, (void*)&bias,
                     (void*)&hA, (void*)&hB, (void*)&out, (void*)&cnt };
    hipLaunchCooperativeKernel((void*)esn_persist, dim3(NBLK), dim3(NTHR),
                               args, 0, stream);
}

// Round 4
// 16796.075 us; speedup vs baseline: 2.2363x; 2.2363x over previous
//
#include <hip/hip_runtime.h>
#include <hip/hip_bf16.h>

#define BB 16
#define TT 1024
#define FF 128
#define RR 2048
#define HALFR 1024
#define NBLK 256
#define NTHR 512

// ---------------- init: h0 + barrier words ----------------
__global__ void init_state_kernel(float* __restrict__ h, const float* __restrict__ start,
                                  unsigned* __restrict__ bar) {
    int idx = blockIdx.x * blockDim.x + threadIdx.x;
    if (idx < BB * RR) h[idx] = start[idx & (RR - 1)];
    if (idx < 2048) bar[idx] = 0u;
}

// ---------------- persistent fp32 ESN kernel ----------------
// 256 blocks x 512 threads, 1 block/CU (cooperative). Block owns 8 rows of
// W_rec, fp32, LDS-resident for all 1024 steps (68 KB LDS). Wave = 4 rows x
// 4 batches; lane owns k = lane*4 + j*256 (contiguous 1KB ds_read_b128 /
// coalesced 1KB global h loads). 16 fp32 accumulators folded by a
// 24-shuffle multi-value butterfly. fp32 everywhere: fp16/bf16 weights are
// numerically ruled out (near-critical recurrence amplifies ~1e-2/step dot
// error to O(1) over T=1024; R3 post-mortem).
__global__ __launch_bounds__(NTHR, 2) void esn_f32(
    const float* __restrict__ inputs,   // [B,T,F]
    const float* __restrict__ Win,      // [R,F]
    const float* __restrict__ Wrec,     // [R,R]
    const float* __restrict__ bias,     // [R]
    float* __restrict__ hA,             // [B,R]
    float* __restrict__ hB,             // [B,R]
    float* __restrict__ out,            // [B,T,HALFR]
    unsigned* __restrict__ bar)
{
    __shared__ __align__(16) float sW[8][RR];     // 64 KB
    __shared__ __align__(16) float sWin[8][FF];   // 4 KB

    const int tid  = threadIdx.x;
    const int lane = tid & 63;
    const int wave = tid >> 6;           // 0..7
    const int rg   = wave & 1;           // row group (4 rows)
    const int bq   = (wave >> 1) * 4;    // batch base 0,4,8,12
    const int r0b  = blockIdx.x * 8;
    const bool proj = (r0b < HALFR);

    // Stage W rows + Win rows into LDS once (reused for all 1024 steps).
    {
        const float4* wsrc = (const float4*)(Wrec + (size_t)r0b * RR);
        float4* wdst = (float4*)sW;
        for (int i = tid; i < (8 * RR) / 4; i += NTHR) wdst[i] = wsrc[i];
        const float4* wis = (const float4*)(Win + (size_t)r0b * FF);
        float4* wid = (float4*)sWin;
        for (int i = tid; i < (8 * FF) / 4; i += NTHR) wid[i] = wis[i];
    }
    __syncthreads();

    const bool hi32 = (lane & 32) != 0;
    const bool hi16 = (lane & 16) != 0;
    const bool hi8  = (lane & 8) != 0;
    const bool hi4  = (lane & 4) != 0;
    const int rOut = r0b + rg * 4 + (hi32 ? 2 : 0) + (hi8 ? 1 : 0);
    const int bOut = bq + (hi16 ? 2 : 0) + (hi4 ? 1 : 0);
    const float myBias = bias[rOut];

    // Two-level barrier; each word on its own 128B line. Group = blockIdx&15
    // -> all 16 members on the same XCD (round-robin dispatch mod 8).
    const unsigned g = blockIdx.x & 15u;
    unsigned* grpCnt      = bar + g * 32;
    unsigned* masterCnt   = bar + 16 * 32;
    unsigned* masterEpoch = bar + 17 * 32;
    unsigned* grpEpoch    = bar + (18 + g) * 32;

    for (int t = 0; t < TT; ++t) {
        const float* hc = (t & 1) ? hB : hA;
        float*       hn = (t & 1) ? hA : hB;

        float acc[4][4];
#pragma unroll
        for (int i = 0; i < 4; ++i)
#pragma unroll
            for (int j = 0; j < 4; ++j) acc[i][j] = 0.0f;

        // Fused input projection (rows < HALFR): lanes 0..31 cover F=128
        if (proj && lane < 32) {
            const int k = lane * 4;
            float4 xv[4];
#pragma unroll
            for (int i = 0; i < 4; ++i)
                xv[i] = *(const float4*)(inputs + ((size_t)(bq + i) * TT + t) * FF + k);
#pragma unroll
            for (int rr = 0; rr < 4; ++rr) {
                const float4 wv = *(const float4*)&sWin[rg * 4 + rr][k];
#pragma unroll
                for (int bb = 0; bb < 4; ++bb) {
                    float a = acc[rr][bb];
                    a = fmaf(wv.x, xv[bb].x, a); a = fmaf(wv.y, xv[bb].y, a);
                    a = fmaf(wv.z, xv[bb].z, a); a = fmaf(wv.w, xv[bb].w, a);
                    acc[rr][bb] = a;
                }
            }
        }

        // Recurrent matmul: k = lane*4 + j*256
#pragma unroll 4
        for (int j = 0; j < 8; ++j) {
            const int k = lane * 4 + j * 256;
            float4 wv[4], hv[4];
#pragma unroll
            for (int i = 0; i < 4; ++i) wv[i] = *(const float4*)&sW[rg * 4 + i][k];
#pragma unroll
            for (int i = 0; i < 4; ++i)
                hv[i] = *(const float4*)(hc + (size_t)(bq + i) * RR + k);
#pragma unroll
            for (int rr = 0; rr < 4; ++rr)
#pragma unroll
                for (int bb = 0; bb < 4; ++bb) {
                    float a = acc[rr][bb];
                    a = fmaf(wv[rr].x, hv[bb].x, a); a = fmaf(wv[rr].y, hv[bb].y, a);
                    a = fmaf(wv[rr].z, hv[bb].z, a); a = fmaf(wv[rr].w, hv[bb].w, a);
                    acc[rr][bb] = a;
                }
        }

        // prefetch h_old for the epilogue (hides L2 latency behind the fold)
        const float hold = hc[(size_t)bOut * RR + rOut];

        // Multi-value fold: 16 accs over 64 lanes in 24 shuffles.
        float s[2][4];
#pragma unroll
        for (int jb = 0; jb < 4; ++jb)
#pragma unroll
            for (int i = 0; i < 2; ++i) {
                const float u = __shfl_xor(acc[i][jb], 32);
                const float v = __shfl_xor(acc[i + 2][jb], 32);
                s[i][jb] = hi32 ? (acc[i + 2][jb] + v) : (acc[i][jb] + u);
            }
        float c2[2][2];
#pragma unroll
        for (int i = 0; i < 2; ++i)
#pragma unroll
            for (int jb = 0; jb < 2; ++jb) {
                const float u = __shfl_xor(s[i][jb], 16);
                const float v = __shfl_xor(s[i][jb + 2], 16);
                c2[i][jb] = hi16 ? (s[i][jb + 2] + v) : (s[i][jb] + u);
            }
        float d2[2];
#pragma unroll
        for (int jb = 0; jb < 2; ++jb) {
            const float u = __shfl_xor(c2[0][jb], 8);
            const float v = __shfl_xor(c2[1][jb], 8);
            d2[jb] = hi8 ? (c2[1][jb] + v) : (c2[0][jb] + u);
        }
        float e;
        {
            const float u = __shfl_xor(d2[0], 4);
            const float v = __shfl_xor(d2[1], 4);
            e = hi4 ? (d2[1] + v) : (d2[0] + u);
        }
        e += __shfl_xor(e, 2);
        e += __shfl_xor(e, 1);

        if ((lane & 3) == 0) {
            const float pre = e + myBias;
            const float vnew = 0.05f * hold + 0.95f * tanhf(pre);
            hn[(size_t)bOut * RR + rOut] = vnew;
            if (rOut >= HALFR)
                out[((size_t)bOut * TT + t) * HALFR + (rOut - HALFR)] = vnew;
        }

        // ---- two-level grid barrier (relaxed spin + one acquire fence) ----
        __syncthreads();
        if (tid == 0) {
            const unsigned tgt = (unsigned)(t + 1);
            const unsigned old = __hip_atomic_fetch_add(grpCnt, 1u, __ATOMIC_ACQ_REL,
                                                        __HIP_MEMORY_SCOPE_AGENT);
            if (old == tgt * 16u - 1u) {                   // last arriver in group
                const unsigned mo = __hip_atomic_fetch_add(masterCnt, 1u, __ATOMIC_ACQ_REL,
                                                           __HIP_MEMORY_SCOPE_AGENT);
                if (mo == tgt * 16u - 1u) {                // last group overall
                    __hip_atomic_store(masterEpoch, tgt, __ATOMIC_RELEASE,
                                       __HIP_MEMORY_SCOPE_AGENT);
                } else {
                    while (__hip_atomic_load(masterEpoch, __ATOMIC_RELAXED,
                                             __HIP_MEMORY_SCOPE_AGENT) < tgt)
                        __builtin_amdgcn_s_sleep(2);
                    __builtin_amdgcn_fence(__ATOMIC_ACQUIRE, "agent");
                }
                __hip_atomic_store(grpEpoch, tgt, __ATOMIC_RELEASE,
                                   __HIP_MEMORY_SCOPE_AGENT);
            } else {
                while (__hip_atomic_load(grpEpoch, __ATOMIC_RELAXED,
                                         __HIP_MEMORY_SCOPE_AGENT) < tgt)
                    __builtin_amdgcn_s_sleep(2);
                __builtin_amdgcn_fence(__ATOMIC_ACQUIRE, "agent");
            }
        }
        __syncthreads();
    }
}

// ---------------- fallback path (proven R1): fp32, 1024 launches ----------------

__global__ void init_h_kernel(float* __restrict__ h, const float* __restrict__ start) {
    int idx = blockIdx.x * blockDim.x + threadIdx.x;
    if (idx < BB * RR) h[idx] = start[idx & (RR - 1)];
}

__global__ __launch_bounds__(512, 2) void step_kernel(
    const float* __restrict__ inputs, const float* __restrict__ Win,
    const float* __restrict__ Wrec, const float* __restrict__ bias,
    const float* __restrict__ h_cur, float* __restrict__ h_next,
    float* __restrict__ out, int t)
{
    const int tid  = threadIdx.x;
    const int wave = tid >> 6;
    const int half = (tid >> 5) & 1;
    const int kl   = tid & 31;
    const int b    = wave * 2 + half;
    const int r0   = blockIdx.x * 8;

    float acc[8];
#pragma unroll
    for (int r = 0; r < 8; ++r) acc[r] = 0.0f;

    if (r0 < HALFR) {
        const float4 in4 = *reinterpret_cast<const float4*>(
            inputs + ((size_t)b * TT + t) * FF + kl * 4);
#pragma unroll
        for (int r = 0; r < 8; ++r) {
            const float4 w4 = *reinterpret_cast<const float4*>(
                Win + (size_t)(r0 + r) * FF + kl * 4);
            acc[r] += in4.x * w4.x + in4.y * w4.y + in4.z * w4.z + in4.w * w4.w;
        }
    }

    const float* hb = h_cur + (size_t)b * RR;
#pragma unroll 2
    for (int j = 0; j < 16; ++j) {
        const int k = kl * 4 + j * 128;
        const float4 h4 = *reinterpret_cast<const float4*>(hb + k);
#pragma unroll
        for (int r = 0; r < 8; ++r) {
            const float4 w4 = *reinterpret_cast<const float4*>(
                Wrec + (size_t)(r0 + r) * RR + k);
            acc[r] = fmaf(h4.x, w4.x, acc[r]);
            acc[r] = fmaf(h4.y, w4.y, acc[r]);
            acc[r] = fmaf(h4.z, w4.z, acc[r]);
            acc[r] = fmaf(h4.w, w4.w, acc[r]);
        }
    }

#pragma unroll
    for (int r = 0; r < 8; ++r) {
        float v = acc[r];
        v += __shfl_xor(v, 1);  v += __shfl_xor(v, 2);
        v += __shfl_xor(v, 4);  v += __shfl_xor(v, 8);
        v += __shfl_xor(v, 16);
        acc[r] = v;
    }

    __shared__ float red[BB][8];
    if (kl == 0) {
#pragma unroll
        for (int r = 0; r < 8; ++r) red[b][r] = acc[r];
    }
    __syncthreads();

    if (tid < BB * 8) {
        const int rr = tid & 7, bb = tid >> 3;
        const int r  = r0 + rr;
        const float pre = red[bb][rr] + bias[r];
        const float h_old = h_cur[(size_t)bb * RR + r];
        const float hn = 0.05f * h_old + 0.95f * tanhf(pre);
        h_next[(size_t)bb * RR + r] = hn;
        if (r0 >= HALFR) out[((size_t)bb * TT + t) * HALFR + (r - HALFR)] = hn;
    }
}

// ---------------- launch ----------------

extern "C" void kernel_launch(void* const* d_in, const int* in_sizes, int n_in,
                              void* d_out, int out_size, void* d_ws, size_t ws_size,
                              hipStream_t stream) {
    const float* inputs = (const float*)d_in[0];   // [B,T,F]
    const float* Win    = (const float*)d_in[1];   // [R,F]
    const float* Wrec   = (const float*)d_in[2];   // [R,R]
    const float* bias   = (const float*)d_in[3];   // [R]
    const float* start  = (const float*)d_in[4];   // [R]
    float* out = (float*)d_out;                    // [B,T,HALFR]

    float* hA = (float*)d_ws;                      // [B,R] fp32
    float* hB = hA + (size_t)BB * RR;              // [B,R] fp32
    unsigned* bar = (unsigned*)(hB + (size_t)BB * RR);
    const size_t need = (size_t)BB * RR * 4 * 2 + 8192;

    if (ws_size >= need) {
        init_state_kernel<<<64, 512, 0, stream>>>(hA, start, bar);
        void* args[] = { (void*)&inputs, (void*)&Win, (void*)&Wrec, (void*)&bias,
                         (void*)&hA, (void*)&hB, (void*)&out, (void*)&bar };
        hipLaunchCooperativeKernel((void*)esn_f32, dim3(NBLK), dim3(NTHR),
                                   args, 0, stream);
    } else {
        init_h_kernel<<<(BB * RR + 255) / 256, 256, 0, stream>>>(hA, start);
        for (int t = 0; t < TT; ++t) {
            const float* hc = (t & 1) ? hB : hA;
            float*       hn = (t & 1) ? hA : hB;
            step_kernel<<<256, 512, 0, stream>>>(inputs, Win, Wrec, bias, hc, hn, out, t);
        }
    }
}

// Round 5
// 6974.042 us; speedup vs baseline: 5.3859x; 2.4084x over previous
//
#include <hip/hip_runtime.h>
#include <hip/hip_bf16.h>

#define BB 16
#define TT 1024
#define FF 128
#define RR 2048
#define HALFR 1024
#define NBLK 256
#define NTHR 512

// ---- coherent (IC-level) memory ops: bypass L1/L2, no fences needed ----
__device__ __forceinline__ float4 ldg_sc4(const float* base, unsigned voff) {
    float4 r;
    asm volatile("global_load_dwordx4 %0, %1, %2 sc0 sc1"
                 : "=v"(r) : "v"(voff), "s"(base) : "memory");
    return r;
}
__device__ __forceinline__ float ldg_sc1(const float* base, unsigned voff) {
    float r;
    asm volatile("global_load_dword %0, %1, %2 sc0 sc1"
                 : "=v"(r) : "v"(voff), "s"(base) : "memory");
    return r;
}
__device__ __forceinline__ void stg_sc1(float* base, unsigned voff, float v) {
    asm volatile("global_store_dword %0, %1, %2 sc0 sc1"
                 :: "v"(voff), "v"(v), "s"(base) : "memory");
}
__device__ __forceinline__ void wait_vm0() {
    asm volatile("s_waitcnt vmcnt(0)" ::: "memory");
}

// ---------------- init: h0 + barrier words ----------------
__global__ void init_state_kernel(float* __restrict__ h, const float* __restrict__ start,
                                  unsigned* __restrict__ bar) {
    int idx = blockIdx.x * blockDim.x + threadIdx.x;
    if (idx < BB * RR) h[idx] = start[idx & (RR - 1)];
    if (idx < 2048) bar[idx] = 0u;
}

// ---------------- persistent fp32 ESN kernel ----------------
// 256 blocks x 512 threads, 1 block/CU (cooperative). Block owns 8 rows of
// W_rec, fp32, LDS-resident for all 1024 steps. Wave = 4 rows x 4 batches;
// all 32 h float4 loads issued up front via sc0/sc1 (coherent, L2-bypass) so
// no agent fences / L2 invalidation are needed anywhere in the loop; the
// barrier is pure relaxed atomics ordered by an explicit vmcnt(0) drain.
__global__ __launch_bounds__(NTHR, 2) void esn_f32(
    const float* __restrict__ inputs,   // [B,T,F]
    const float* __restrict__ Win,      // [R,F]
    const float* __restrict__ Wrec,     // [R,R]
    const float* __restrict__ bias,     // [R]
    float* __restrict__ hA,             // [B,R]
    float* __restrict__ hB,             // [B,R]
    float* __restrict__ out,            // [B,T,HALFR]
    unsigned* __restrict__ bar)
{
    __shared__ __align__(16) float sW[8][RR];     // 64 KB
    __shared__ __align__(16) float sWin[8][FF];   // 4 KB

    const int tid  = threadIdx.x;
    const int lane = tid & 63;
    const int wave = tid >> 6;           // 0..7
    const int rg   = wave & 1;           // row group (4 rows)
    const int bq   = (wave >> 1) * 4;    // batch base 0,4,8,12
    const int r0b  = blockIdx.x * 8;
    const bool proj = (r0b < HALFR);

    // Stage W + Win into LDS once (reused for all 1024 steps).
    {
        const float4* wsrc = (const float4*)(Wrec + (size_t)r0b * RR);
        float4* wdst = (float4*)sW;
        for (int i = tid; i < (8 * RR) / 4; i += NTHR) wdst[i] = wsrc[i];
        const float4* wis = (const float4*)(Win + (size_t)r0b * FF);
        float4* wid = (float4*)sWin;
        for (int i = tid; i < (8 * FF) / 4; i += NTHR) wid[i] = wis[i];
    }
    __syncthreads();

    const bool hi32 = (lane & 32) != 0;
    const bool hi16 = (lane & 16) != 0;
    const bool hi8  = (lane & 8) != 0;
    const bool hi4  = (lane & 4) != 0;
    const int rOut = r0b + rg * 4 + (hi32 ? 2 : 0) + (hi8 ? 1 : 0);
    const int bOut = bq + (hi16 ? 2 : 0) + (hi4 ? 1 : 0);
    const float myBias = bias[rOut];

    // Loop-invariant byte offsets for the coherent h accesses.
    unsigned voff[4][8];
#pragma unroll
    for (int i = 0; i < 4; ++i)
#pragma unroll
        for (int j = 0; j < 8; ++j)
            voff[i][j] = (unsigned)((bq + i) * RR * 4 + j * 1024 + lane * 16);
    const unsigned voffOld = (unsigned)((bOut * RR + rOut) * 4);

    // Two-level barrier; each word on its own 128B line.
    const unsigned g = blockIdx.x & 15u;
    unsigned* grpCnt      = bar + g * 32;
    unsigned* masterCnt   = bar + 16 * 32;
    unsigned* masterEpoch = bar + 17 * 32;
    unsigned* grpEpoch    = bar + (18 + g) * 32;

    for (int t = 0; t < TT; ++t) {
        const float* hc = (t & 1) ? hB : hA;
        float*       hn = (t & 1) ? hA : hB;

        // 1) Issue ALL coherent h loads up front (33 in flight).
        float4 hbuf[4][8];
#pragma unroll
        for (int i = 0; i < 4; ++i)
#pragma unroll
            for (int j = 0; j < 8; ++j)
                hbuf[i][j] = ldg_sc4(hc, voff[i][j]);
        const float hold = ldg_sc1(hc, voffOld);

        float acc[4][4];
#pragma unroll
        for (int i = 0; i < 4; ++i)
#pragma unroll
            for (int j = 0; j < 4; ++j) acc[i][j] = 0.0f;

        // 2) Input projection overlaps the h-load latency (L2-warm loads).
        if (proj && lane < 32) {
            const int k = lane * 4;
            float4 xv[4];
#pragma unroll
            for (int i = 0; i < 4; ++i)
                xv[i] = *(const float4*)(inputs + ((size_t)(bq + i) * TT + t) * FF + k);
#pragma unroll
            for (int rr = 0; rr < 4; ++rr) {
                const float4 wv = *(const float4*)&sWin[rg * 4 + rr][k];
#pragma unroll
                for (int bb = 0; bb < 4; ++bb) {
                    float a = acc[rr][bb];
                    a = fmaf(wv.x, xv[bb].x, a); a = fmaf(wv.y, xv[bb].y, a);
                    a = fmaf(wv.z, xv[bb].z, a); a = fmaf(wv.w, xv[bb].w, a);
                    acc[rr][bb] = a;
                }
            }
        }

        // 3) Drain the prefetch batch, then the MAC loop (W from LDS).
        wait_vm0();
#pragma unroll
        for (int j = 0; j < 8; ++j) {
            const int k = lane * 4 + j * 256;
            float4 wv[4];
#pragma unroll
            for (int i = 0; i < 4; ++i) wv[i] = *(const float4*)&sW[rg * 4 + i][k];
#pragma unroll
            for (int rr = 0; rr < 4; ++rr)
#pragma unroll
                for (int bb = 0; bb < 4; ++bb) {
                    float a = acc[rr][bb];
                    a = fmaf(wv[rr].x, hbuf[bb][j].x, a);
                    a = fmaf(wv[rr].y, hbuf[bb][j].y, a);
                    a = fmaf(wv[rr].z, hbuf[bb][j].z, a);
                    a = fmaf(wv[rr].w, hbuf[bb][j].w, a);
                    acc[rr][bb] = a;
                }
        }

        // 4) Multi-value fold: 16 accs over 64 lanes in 24 shuffles (R4-verified).
        float s[2][4];
#pragma unroll
        for (int jb = 0; jb < 4; ++jb)
#pragma unroll
            for (int i = 0; i < 2; ++i) {
                const float u = __shfl_xor(acc[i][jb], 32);
                const float v = __shfl_xor(acc[i + 2][jb], 32);
                s[i][jb] = hi32 ? (acc[i + 2][jb] + v) : (acc[i][jb] + u);
            }
        float c2[2][2];
#pragma unroll
        for (int i = 0; i < 2; ++i)
#pragma unroll
            for (int jb = 0; jb < 2; ++jb) {
                const float u = __shfl_xor(s[i][jb], 16);
                const float v = __shfl_xor(s[i][jb + 2], 16);
                c2[i][jb] = hi16 ? (s[i][jb + 2] + v) : (s[i][jb] + u);
            }
        float d2[2];
#pragma unroll
        for (int jb = 0; jb < 2; ++jb) {
            const float u = __shfl_xor(c2[0][jb], 8);
            const float v = __shfl_xor(c2[1][jb], 8);
            d2[jb] = hi8 ? (c2[1][jb] + v) : (c2[0][jb] + u);
        }
        float e;
        {
            const float u = __shfl_xor(d2[0], 4);
            const float v = __shfl_xor(d2[1], 4);
            e = hi4 ? (d2[1] + v) : (d2[0] + u);
        }
        e += __shfl_xor(e, 2);
        e += __shfl_xor(e, 1);

        // 5) Epilogue: coherent h_next store; cached out store.
        if ((lane & 3) == 0) {
            const float pre = e + myBias;
            const float vnew = 0.05f * hold + 0.95f * tanhf(pre);
            stg_sc1(hn, voffOld, vnew);
            if (rOut >= HALFR)
                out[((size_t)bOut * TT + t) * HALFR + (rOut - HALFR)] = vnew;
        }

        // 6) Drain stores (visibility at coherence point), then relaxed barrier.
        wait_vm0();
        __syncthreads();
        if (tid == 0) {
            const unsigned tgt = (unsigned)(t + 1);
            const unsigned old = __hip_atomic_fetch_add(grpCnt, 1u, __ATOMIC_RELAXED,
                                                        __HIP_MEMORY_SCOPE_AGENT);
            if (old == tgt * 16u - 1u) {                   // last arriver in group
                const unsigned mo = __hip_atomic_fetch_add(masterCnt, 1u, __ATOMIC_RELAXED,
                                                           __HIP_MEMORY_SCOPE_AGENT);
                if (mo == tgt * 16u - 1u) {                // last group overall
                    __hip_atomic_store(masterEpoch, tgt, __ATOMIC_RELAXED,
                                       __HIP_MEMORY_SCOPE_AGENT);
                } else {
                    while (__hip_atomic_load(masterEpoch, __ATOMIC_RELAXED,
                                             __HIP_MEMORY_SCOPE_AGENT) < tgt)
                        __builtin_amdgcn_s_sleep(2);
                }
                __hip_atomic_store(grpEpoch, tgt, __ATOMIC_RELAXED,
                                   __HIP_MEMORY_SCOPE_AGENT);
            } else {
                while (__hip_atomic_load(grpEpoch, __ATOMIC_RELAXED,
                                         __HIP_MEMORY_SCOPE_AGENT) < tgt)
                    __builtin_amdgcn_s_sleep(2);
            }
        }
        __syncthreads();
    }
}

// ---------------- fallback path (proven R1): fp32, 1024 launches ----------------

__global__ void init_h_kernel(float* __restrict__ h, const float* __restrict__ start) {
    int idx = blockIdx.x * blockDim.x + threadIdx.x;
    if (idx < BB * RR) h[idx] = start[idx & (RR - 1)];
}

__global__ __launch_bounds__(512, 2) void step_kernel(
    const float* __restrict__ inputs, const float* __restrict__ Win,
    const float* __restrict__ Wrec, const float* __restrict__ bias,
    const float* __restrict__ h_cur, float* __restrict__ h_next,
    float* __restrict__ out, int t)
{
    const int tid  = threadIdx.x;
    const int wave = tid >> 6;
    const int half = (tid >> 5) & 1;
    const int kl   = tid & 31;
    const int b    = wave * 2 + half;
    const int r0   = blockIdx.x * 8;

    float acc[8];
#pragma unroll
    for (int r = 0; r < 8; ++r) acc[r] = 0.0f;

    if (r0 < HALFR) {
        const float4 in4 = *reinterpret_cast<const float4*>(
            inputs + ((size_t)b * TT + t) * FF + kl * 4);
#pragma unroll
        for (int r = 0; r < 8; ++r) {
            const float4 w4 = *reinterpret_cast<const float4*>(
                Win + (size_t)(r0 + r) * FF + kl * 4);
            acc[r] += in4.x * w4.x + in4.y * w4.y + in4.z * w4.z + in4.w * w4.w;
        }
    }

    const float* hb = h_cur + (size_t)b * RR;
#pragma unroll 2
    for (int j = 0; j < 16; ++j) {
        const int k = kl * 4 + j * 128;
        const float4 h4 = *reinterpret_cast<const float4*>(hb + k);
#pragma unroll
        for (int r = 0; r < 8; ++r) {
            const float4 w4 = *reinterpret_cast<const float4*>(
                Wrec + (size_t)(r0 + r) * RR + k);
            acc[r] = fmaf(h4.x, w4.x, acc[r]);
            acc[r] = fmaf(h4.y, w4.y, acc[r]);
            acc[r] = fmaf(h4.z, w4.z, acc[r]);
            acc[r] = fmaf(h4.w, w4.w, acc[r]);
        }
    }

#pragma unroll
    for (int r = 0; r < 8; ++r) {
        float v = acc[r];
        v += __shfl_xor(v, 1);  v += __shfl_xor(v, 2);
        v += __shfl_xor(v, 4);  v += __shfl_xor(v, 8);
        v += __shfl_xor(v, 16);
        acc[r] = v;
    }

    __shared__ float red[BB][8];
    if (kl == 0) {
#pragma unroll
        for (int r = 0; r < 8; ++r) red[b][r] = acc[r];
    }
    __syncthreads();

    if (tid < BB * 8) {
        const int rr = tid & 7, bb = tid >> 3;
        const int r  = r0 + rr;
        const float pre = red[bb][rr] + bias[r];
        const float h_old = h_cur[(size_t)bb * RR + r];
        const float hn = 0.05f * h_old + 0.95f * tanhf(pre);
        h_next[(size_t)bb * RR + r] = hn;
        if (r0 >= HALFR) out[((size_t)bb * TT + t) * HALFR + (r - HALFR)] = hn;
    }
}

// ---------------- launch ----------------

extern "C" void kernel_launch(void* const* d_in, const int* in_sizes, int n_in,
                              void* d_out, int out_size, void* d_ws, size_t ws_size,
                              hipStream_t stream) {
    const float* inputs = (const float*)d_in[0];   // [B,T,F]
    const float* Win    = (const float*)d_in[1];   // [R,F]
    const float* Wrec   = (const float*)d_in[2];   // [R,R]
    const float* bias   = (const float*)d_in[3];   // [R]
    const float* start  = (const float*)d_in[4];   // [R]
    float* out = (float*)d_out;                    // [B,T,HALFR]

    float* hA = (float*)d_ws;                      // [B,R] fp32
    float* hB = hA + (size_t)BB * RR;              // [B,R] fp32
    unsigned* bar = (unsigned*)(hB + (size_t)BB * RR);
    const size_t need = (size_t)BB * RR * 4 * 2 + 8192;

    if (ws_size >= need) {
        init_state_kernel<<<64, 512, 0, stream>>>(hA, start, bar);
        void* args[] = { (void*)&inputs, (void*)&Win, (void*)&Wrec, (void*)&bias,
                         (void*)&hA, (void*)&hB, (void*)&out, (void*)&bar };
        hipLaunchCooperativeKernel((void*)esn_f32, dim3(NBLK), dim3(NTHR),
                                   args, 0, stream);
    } else {
        init_h_kernel<<<(BB * RR + 255) / 256, 256, 0, stream>>>(hA, start);
        for (int t = 0; t < TT; ++t) {
            const float* hc = (t & 1) ? hB : hA;
            float*       hn = (t & 1) ? hA : hB;
            step_kernel<<<256, 512, 0, stream>>>(inputs, Win, Wrec, bias, hc, hn, out, t);
        }
    }
}